// Round 1
// baseline (421.219 us; speedup 1.0000x reference)
//
#include <hip/hip_runtime.h>
#include <hip/hip_bf16.h>
#include <stdint.h>

// TripleAttention on MI355X (gfx950).
// B=1, N=2048, C=1024, H=16, hd=64.
//
// Accuracy strategy: scores s = (q1.k1)*(q2.k2) have row-max ~2500; softmax
// needs ~1e-5 RELATIVE score accuracy. bf16 MFMA alone is 2^-9 -> fail.
// => split-bf16 (hi+lo) 3-term MFMA for q1/q2/k1/k2 projections and both
//    Gram matrices (fp32-class accuracy at 1/3 bf16 rate).
// v / PV / LN / out-proj are insensitive -> plain bf16 MFMA.

#define N_SEQ 2048
#define CDIM  1024
#define NHEAD 16
#define HDIM  64

typedef __attribute__((ext_vector_type(8))) short bfrag;  // 8 bf16 (4 VGPR)
typedef __attribute__((ext_vector_type(4))) float f4;     // MFMA 16x16 acc
typedef unsigned short u16;

#define MFMA16(a, b, c) __builtin_amdgcn_mfma_f32_16x16x32_bf16((a), (b), (c), 0, 0, 0)

__device__ __forceinline__ float bf2f(u16 u) {
  union { unsigned int i; float f; } c; c.i = ((unsigned int)u) << 16; return c.f;
}
__device__ __forceinline__ u16 f2bf(float f) {  // RNE
  union { float f; unsigned int i; } c; c.f = f;
  unsigned int i = c.i;
  return (u16)((i + 0x7FFFu + ((i >> 16) & 1u)) >> 16);
}

__device__ __forceinline__ void gld16(const void* g, void* lds) {
  __builtin_amdgcn_global_load_lds(
      (const __attribute__((address_space(1))) void*)g,
      (__attribute__((address_space(3))) void*)lds, 16, 0, 0);
}

// ---------------- split x into hi/lo bf16 ----------------
__global__ __launch_bounds__(256) void k_split_x(
    const float* __restrict__ x, u16* __restrict__ xh, u16* __restrict__ xl) {
  int i = (blockIdx.x * 256 + threadIdx.x) * 4;
  float4 v = *(const float4*)(x + i);
  float vv[4] = {v.x, v.y, v.z, v.w};
  ushort4 h, l;
  u16 hh[4], ll[4];
#pragma unroll
  for (int j = 0; j < 4; j++) {
    hh[j] = f2bf(vv[j]);
    ll[j] = f2bf(vv[j] - bf2f(hh[j]));
  }
  h.x = hh[0]; h.y = hh[1]; h.z = hh[2]; h.w = hh[3];
  l.x = ll[0]; l.y = ll[1]; l.z = ll[2]; l.w = ll[3];
  *(ushort4*)(xh + i) = h;
  *(ushort4*)(xl + i) = l;
}

// ------- transpose + split the 6 weight matrices: Wt[n][k] hi (all), lo (w<4) -------
__global__ __launch_bounds__(256) void k_wsplit(
    const float* __restrict__ W0, const float* __restrict__ W1,
    const float* __restrict__ W2, const float* __restrict__ W3,
    const float* __restrict__ W4, const float* __restrict__ W5,
    u16* __restrict__ wth, u16* __restrict__ wtl) {
  __shared__ float tile[64][65];
  int wz = blockIdx.z;
  const float* W = wz == 0 ? W0 : wz == 1 ? W1 : wz == 2 ? W2 : wz == 3 ? W3 : wz == 4 ? W4 : W5;
  int kb = blockIdx.x * 64, nb = blockIdx.y * 64;
  int t = threadIdx.x;
  int r0 = t >> 4, c0 = (t & 15) * 4;
#pragma unroll
  for (int i = 0; i < 4; i++) {
    int r = r0 + i * 16;
    float4 v = *(const float4*)(W + (size_t)(kb + r) * CDIM + nb + c0);
    tile[r][c0 + 0] = v.x; tile[r][c0 + 1] = v.y; tile[r][c0 + 2] = v.z; tile[r][c0 + 3] = v.w;
  }
  __syncthreads();
#pragma unroll
  for (int i = 0; i < 4; i++) {
    int wn = (t >> 4) + i * 16;   // n within tile
    int wk = (t & 15) * 4;        // k within tile
    ushort4 h, l;
    u16 hh[4], ll[4];
#pragma unroll
    for (int j = 0; j < 4; j++) {
      float v = tile[wk + j][wn];
      hh[j] = f2bf(v);
      ll[j] = f2bf(v - bf2f(hh[j]));
    }
    h.x = hh[0]; h.y = hh[1]; h.z = hh[2]; h.w = hh[3];
    l.x = ll[0]; l.y = ll[1]; l.z = ll[2]; l.w = ll[3];
    size_t off = ((size_t)wz * CDIM + nb + wn) * CDIM + kb + wk;
    *(ushort4*)(wth + off) = h;
    if (wz < 4) *(ushort4*)(wtl + off) = l;
  }
}

// ------------- fused 5-projection GEMM: P_w = x + x@W_w + b_w -------------
// grid (40,16): w = bx/8, 128x128 tile.  w<4: 3 split phases, split output.
// w==4: 1 phase, output transposed bf16 (vT[c][n]) for PV B-fragments.
__global__ __launch_bounds__(256, 2) void k_proj(
    const u16* __restrict__ xh, const u16* __restrict__ xl,
    const u16* __restrict__ wth, const u16* __restrict__ wtl,
    const float* __restrict__ x,
    const float* __restrict__ b0, const float* __restrict__ b1,
    const float* __restrict__ b2, const float* __restrict__ b3,
    const float* __restrict__ b4,
    u16* __restrict__ qh, u16* __restrict__ ql, u16* __restrict__ vT) {
  __shared__ u16 sA[128 * 64];
  __shared__ u16 sB[128 * 64];
  int t = threadIdx.x;
  int w = blockIdx.x >> 3;
  int n0 = (blockIdx.x & 7) * 128;
  int m0 = blockIdx.y * 128;
  int lane = t & 63, wid = t >> 6;
  int wm = (wid >> 1) * 64, wn = (wid & 1) * 64;
  int lr = lane & 15, lg = lane >> 4;

  f4 acc[4][4];
#pragma unroll
  for (int i = 0; i < 4; i++)
#pragma unroll
    for (int j = 0; j < 4; j++) acc[i][j] = (f4)0.0f;

  const int nphase = (w < 4) ? 3 : 1;
  const u16* wb = wth + (size_t)w * CDIM * CDIM;
  const u16* wl = wtl + (size_t)w * CDIM * CDIM;

  int srow = t >> 3;          // 0..31
  int scol = (t & 7) * 8;     // elem col
  int soff = srow * 64 + scol;

  for (int p = 0; p < nphase; p++) {
    const u16* A = (p == 2) ? xl : xh;
    const u16* B = (p == 1) ? wl : wb;
    for (int kt = 0; kt < CDIM; kt += 64) {
#pragma unroll
      for (int c = 0; c < 4; c++) {
        gld16(A + (size_t)(m0 + srow + c * 32) * CDIM + kt + scol, (u16*)sA + soff + c * 2048);
        gld16(B + (size_t)(n0 + srow + c * 32) * CDIM + kt + scol, (u16*)sB + soff + c * 2048);
      }
      __syncthreads();
#pragma unroll
      for (int kk = 0; kk < 2; kk++) {
        bfrag af[4], bv[4];
#pragma unroll
        for (int mi = 0; mi < 4; mi++)
          af[mi] = *(const bfrag*)(sA + (wm + mi * 16 + lr) * 64 + kk * 32 + lg * 8);
#pragma unroll
        for (int ni = 0; ni < 4; ni++)
          bv[ni] = *(const bfrag*)(sB + (wn + ni * 16 + lr) * 64 + kk * 32 + lg * 8);
#pragma unroll
        for (int mi = 0; mi < 4; mi++)
#pragma unroll
          for (int ni = 0; ni < 4; ni++)
            acc[mi][ni] = MFMA16(af[mi], bv[ni], acc[mi][ni]);
      }
      __syncthreads();
    }
  }

  const float* bias = w == 0 ? b0 : w == 1 ? b1 : w == 2 ? b2 : w == 3 ? b3 : b4;
#pragma unroll
  for (int mi = 0; mi < 4; mi++) {
#pragma unroll
    for (int ni = 0; ni < 4; ni++) {
      int col = n0 + wn + ni * 16 + lr;       // 0..1023 within this weight
      int rowb = m0 + wm + mi * 16 + lg * 4;
      float vv[4];
#pragma unroll
      for (int r = 0; r < 4; r++)
        vv[r] = acc[mi][ni][r] + x[(size_t)(rowb + r) * CDIM + col] + bias[col];
      if (w < 4) {
#pragma unroll
        for (int r = 0; r < 4; r++) {
          u16 h = f2bf(vv[r]);
          u16 l = f2bf(vv[r] - bf2f(h));
          qh[((size_t)w * N_SEQ + rowb + r) * CDIM + col] = h;
          ql[((size_t)w * N_SEQ + rowb + r) * CDIM + col] = l;
        }
      } else {
        ushort4 pv;
        pv.x = f2bf(vv[0]); pv.y = f2bf(vv[1]); pv.z = f2bf(vv[2]); pv.w = f2bf(vv[3]);
        *(ushort4*)(vT + (size_t)col * N_SEQ + rowb) = pv;
      }
    }
  }
}

// ---------------- flash attention, split-bf16 scores ----------------
// grid (32,16): head = by, 64 q-rows per block, 4 waves x 16 rows.
// K/V fragments loaded straight from global (L2-resident); P transposed
// through a per-wave XOR-swizzled LDS bounce.
__global__ __launch_bounds__(256, 2) void k_attn(
    const u16* __restrict__ qkh, const u16* __restrict__ qkl,
    const u16* __restrict__ vT, float* __restrict__ o) {
  __shared__ u16 pbuf[4][16 * 64];
  int h = blockIdx.y;
  int qb = blockIdx.x * 64;
  int t = threadIdx.x, lane = t & 63, wv = t >> 6, lr = lane & 15, lg = lane >> 4;
  const size_t NC = (size_t)N_SEQ * CDIM;

  const u16* q1h = qkh;          const u16* q1l = qkl;
  const u16* q2h = qkh + NC;     const u16* q2l = qkl + NC;
  const u16* k1h = qkh + 2 * NC; const u16* k1l = qkl + 2 * NC;
  const u16* k2h = qkh + 3 * NC; const u16* k2l = qkl + 3 * NC;

  int qrow = qb + wv * 16 + lr;
  size_t qoff = (size_t)qrow * CDIM + h * HDIM + lg * 8;
  bfrag a1h[2], a1l[2], a2h[2], a2l[2];
#pragma unroll
  for (int ks = 0; ks < 2; ks++) {
    a1h[ks] = *(const bfrag*)(q1h + qoff + ks * 32);
    a1l[ks] = *(const bfrag*)(q1l + qoff + ks * 32);
    a2h[ks] = *(const bfrag*)(q2h + qoff + ks * 32);
    a2l[ks] = *(const bfrag*)(q2l + qoff + ks * 32);
  }

  float mrow[4], lrow[4];
  f4 accO[4];
#pragma unroll
  for (int r = 0; r < 4; r++) { mrow[r] = -1e30f; lrow[r] = 0.f; }
#pragma unroll
  for (int d = 0; d < 4; d++) accO[d] = (f4)0.0f;

  u16* pb = &pbuf[wv][0];

  for (int kt = 0; kt < N_SEQ; kt += 64) {
    f4 s1[4], s2[4];
#pragma unroll
    for (int i = 0; i < 4; i++) { s1[i] = (f4)0.0f; s2[i] = (f4)0.0f; }
#pragma unroll
    for (int kv = 0; kv < 4; kv++) {
      size_t koff = (size_t)(kt + kv * 16 + lr) * CDIM + h * HDIM + lg * 8;
#pragma unroll
      for (int ks = 0; ks < 2; ks++) {
        bfrag b1h = *(const bfrag*)(k1h + koff + ks * 32);
        bfrag b1l = *(const bfrag*)(k1l + koff + ks * 32);
        bfrag b2h = *(const bfrag*)(k2h + koff + ks * 32);
        bfrag b2l = *(const bfrag*)(k2l + koff + ks * 32);
        s1[kv] = MFMA16(a1h[ks], b1h, s1[kv]);
        s1[kv] = MFMA16(a1h[ks], b1l, s1[kv]);
        s1[kv] = MFMA16(a1l[ks], b1h, s1[kv]);
        s2[kv] = MFMA16(a2h[ks], b2h, s2[kv]);
        s2[kv] = MFMA16(a2h[ks], b2l, s2[kv]);
        s2[kv] = MFMA16(a2l[ks], b2h, s2[kv]);
      }
    }
    // s = s1 .* s2 ; online softmax per q-row (rows = lg*4+r, cols = kv*16+lr)
#pragma unroll
    for (int kv = 0; kv < 4; kv++) s1[kv] *= s2[kv];
#pragma unroll
    for (int r = 0; r < 4; r++) {
      float pm = fmaxf(fmaxf(s1[0][r], s1[1][r]), fmaxf(s1[2][r], s1[3][r]));
#pragma unroll
      for (int d = 1; d < 16; d <<= 1) pm = fmaxf(pm, __shfl_xor(pm, d, 64));
      float mnew = fmaxf(mrow[r], pm);
      float scale = __expf(mrow[r] - mnew);
      mrow[r] = mnew;
      float rs = 0.f;
#pragma unroll
      for (int kv = 0; kv < 4; kv++) {
        float p = __expf(s1[kv][r] - mnew);
        s1[kv][r] = p;
        rs += p;
      }
#pragma unroll
      for (int d = 1; d < 16; d <<= 1) rs += __shfl_xor(rs, d, 64);
      lrow[r] = lrow[r] * scale + rs;
#pragma unroll
      for (int dg = 0; dg < 4; dg++) accO[dg][r] *= scale;
    }
    // P -> LDS (bf16), XOR-swizzled so the b128 A-frag read is ~conflict-free
#pragma unroll
    for (int kv = 0; kv < 4; kv++) {
#pragma unroll
      for (int r = 0; r < 4; r++) {
        int prow = lg * 4 + r;
        int off = (prow * 128 + (kv * 16 + lr) * 2) ^ ((prow & 7) << 4);
        *(u16*)((char*)pb + off) = f2bf(s1[kv][r]);
      }
    }
    // PV: A-frag from LDS, B-frag straight from vT (16B contiguous)
#pragma unroll
    for (int ks = 0; ks < 2; ks++) {
      bfrag pa = *(const bfrag*)((char*)pb + ((lr * 128 + ks * 64 + lg * 16) ^ ((lr & 7) << 4)));
#pragma unroll
      for (int dg = 0; dg < 4; dg++) {
        bfrag vb = *(const bfrag*)(vT + (size_t)(h * HDIM + dg * 16 + lr) * N_SEQ + kt + ks * 32 + lg * 8);
        accO[dg] = MFMA16(pa, vb, accO[dg]);
      }
    }
  }
#pragma unroll
  for (int dg = 0; dg < 4; dg++) {
#pragma unroll
    for (int r = 0; r < 4; r++) {
      int row = qb + wv * 16 + lg * 4 + r;
      int col = h * HDIM + dg * 16 + lr;
      o[(size_t)row * CDIM + col] = accO[dg][r] / lrow[r];
    }
  }
}

// ---------------- LayerNorm (one row per block) ----------------
__global__ __launch_bounds__(256) void k_ln(
    const float* __restrict__ o, const float* __restrict__ g,
    const float* __restrict__ b, u16* __restrict__ oln) {
  __shared__ float rs[4], rs2[4];
  int row = blockIdx.x, t = threadIdx.x;
  float4 v = *(const float4*)(o + (size_t)row * CDIM + t * 4);
  float s = v.x + v.y + v.z + v.w;
  float s2 = v.x * v.x + v.y * v.y + v.z * v.z + v.w * v.w;
#pragma unroll
  for (int d = 1; d < 64; d <<= 1) {
    s += __shfl_xor(s, d, 64);
    s2 += __shfl_xor(s2, d, 64);
  }
  int wv = t >> 6;
  if ((t & 63) == 0) { rs[wv] = s; rs2[wv] = s2; }
  __syncthreads();
  s = rs[0] + rs[1] + rs[2] + rs[3];
  s2 = rs2[0] + rs2[1] + rs2[2] + rs2[3];
  float mu = s * (1.0f / CDIM);
  float var = s2 * (1.0f / CDIM) - mu * mu;
  float inv = rsqrtf(var + 1e-5f);
  float vals[4] = {v.x, v.y, v.z, v.w};
  ushort4 r4;
  u16 rr[4];
#pragma unroll
  for (int j = 0; j < 4; j++) {
    int col = t * 4 + j;
    rr[j] = f2bf((vals[j] - mu) * inv * g[col] + b[col]);
  }
  r4.x = rr[0]; r4.y = rr[1]; r4.z = rr[2]; r4.w = rr[3];
  *(ushort4*)(oln + (size_t)row * CDIM + t * 4) = r4;
}

// ---------------- out = oln @ W_out + b_out (plain bf16) ----------------
__global__ __launch_bounds__(256, 2) void k_ogemm(
    const u16* __restrict__ A, const u16* __restrict__ Bw,
    const float* __restrict__ bias, float* __restrict__ out) {
  __shared__ u16 sA[128 * 64];
  __shared__ u16 sB[128 * 64];
  int t = threadIdx.x;
  int n0 = blockIdx.x * 128, m0 = blockIdx.y * 128;
  int lane = t & 63, wid = t >> 6;
  int wm = (wid >> 1) * 64, wn = (wid & 1) * 64;
  int lr = lane & 15, lg = lane >> 4;
  f4 acc[4][4];
#pragma unroll
  for (int i = 0; i < 4; i++)
#pragma unroll
    for (int j = 0; j < 4; j++) acc[i][j] = (f4)0.0f;
  int srow = t >> 3, scol = (t & 7) * 8, soff = srow * 64 + scol;
  for (int kt = 0; kt < CDIM; kt += 64) {
#pragma unroll
    for (int c = 0; c < 4; c++) {
      gld16(A + (size_t)(m0 + srow + c * 32) * CDIM + kt + scol, (u16*)sA + soff + c * 2048);
      gld16(Bw + (size_t)(n0 + srow + c * 32) * CDIM + kt + scol, (u16*)sB + soff + c * 2048);
    }
    __syncthreads();
#pragma unroll
    for (int kk = 0; kk < 2; kk++) {
      bfrag af[4], bv[4];
#pragma unroll
      for (int mi = 0; mi < 4; mi++)
        af[mi] = *(const bfrag*)(sA + (wm + mi * 16 + lr) * 64 + kk * 32 + lg * 8);
#pragma unroll
      for (int ni = 0; ni < 4; ni++)
        bv[ni] = *(const bfrag*)(sB + (wn + ni * 16 + lr) * 64 + kk * 32 + lg * 8);
#pragma unroll
      for (int mi = 0; mi < 4; mi++)
#pragma unroll
        for (int ni = 0; ni < 4; ni++)
          acc[mi][ni] = MFMA16(af[mi], bv[ni], acc[mi][ni]);
    }
    __syncthreads();
  }
#pragma unroll
  for (int mi = 0; mi < 4; mi++) {
#pragma unroll
    for (int ni = 0; ni < 4; ni++) {
      int col = n0 + wn + ni * 16 + lr;
      int rowb = m0 + wm + mi * 16 + lg * 4;
#pragma unroll
      for (int r = 0; r < 4; r++)
        out[(size_t)(rowb + r) * CDIM + col] = acc[mi][ni][r] + bias[col];
    }
  }
}

extern "C" void kernel_launch(void* const* d_in, const int* in_sizes, int n_in,
                              void* d_out, int out_size, void* d_ws, size_t ws_size,
                              hipStream_t stream) {
  const float* x   = (const float*)d_in[0];
  const float* Wq1 = (const float*)d_in[1];  const float* bq1 = (const float*)d_in[2];
  const float* Wq2 = (const float*)d_in[3];  const float* bq2 = (const float*)d_in[4];
  const float* Wk1 = (const float*)d_in[5];  const float* bk1 = (const float*)d_in[6];
  const float* Wk2 = (const float*)d_in[7];  const float* bk2 = (const float*)d_in[8];
  const float* Wv  = (const float*)d_in[9];  const float* bv  = (const float*)d_in[10];
  const float* Wo  = (const float*)d_in[11]; const float* bo  = (const float*)d_in[12];
  const float* lng = (const float*)d_in[13]; const float* lnb = (const float*)d_in[14];

  char* w = (char*)d_ws;  // 64 MiB total, with two safe aliases
  u16* xh  = (u16*)(w + (0ull << 20));    // 4 MiB
  u16* xl  = (u16*)(w + (4ull << 20));    // 4 MiB
  u16* wth = (u16*)(w + (8ull << 20));    // 12 MiB [6][C][C]
  u16* wtl = (u16*)(w + (20ull << 20));   // 8 MiB  [4][C][C]
  u16* qsh = (u16*)(w + (28ull << 20));   // 16 MiB [4][N][C]  q1,q2,k1,k2 hi
  u16* qsl = (u16*)(w + (44ull << 20));   // 16 MiB lo
  u16* vT  = (u16*)(w + (60ull << 20));   // 4 MiB  [C][N]
  float* o = (float*)(w + (0ull << 20));  // 8 MiB, aliases xh/xl (dead after proj)
  u16* oln = (u16*)(w + (20ull << 20));   // 4 MiB, aliases wtl (dead after proj)

  k_split_x<<<2048, 256, 0, stream>>>(x, xh, xl);
  k_wsplit<<<dim3(16, 16, 6), 256, 0, stream>>>(Wq1, Wq2, Wk1, Wk2, Wv, Wo, wth, wtl);
  k_proj<<<dim3(40, 16), 256, 0, stream>>>(xh, xl, wth, wtl, x,
                                           bq1, bq2, bk1, bk2, bv, qsh, qsl, vT);
  k_attn<<<dim3(32, 16), 256, 0, stream>>>(qsh, qsl, vT, o);
  k_ln<<<2048, 256, 0, stream>>>(o, lng, lnb, oln);
  k_ogemm<<<dim3(8, 16), 256, 0, stream>>>(oln, wth + 5ull * CDIM * CDIM, bo, (float*)d_out);
}

// Round 2
// 252.884 us; speedup vs baseline: 1.6657x; 1.6657x over previous
//
#include <hip/hip_runtime.h>
#include <hip/hip_bf16.h>
#include <stdint.h>

// TripleAttention on MI355X (gfx950).
// B=1, N=2048, C=1024, H=16, hd=64.
//
// Accuracy strategy: scores s = (q1.k1)*(q2.k2) have row-max ~2500; softmax
// needs ~1e-5 RELATIVE score accuracy. bf16 MFMA alone is 2^-9 -> fail.
// => split-bf16 (hi+lo) 3-term MFMA for q1/q2/k1/k2 projections and both
//    Gram matrices (fp32-class accuracy at 1/3 bf16 rate).
// v / PV / LN / out-proj are insensitive -> plain bf16 MFMA.

#define N_SEQ 2048
#define CDIM  1024
#define NHEAD 16
#define HDIM  64

typedef __attribute__((ext_vector_type(8))) short bfrag;  // 8 bf16 (4 VGPR)
typedef __attribute__((ext_vector_type(4))) float f4;     // MFMA 16x16 acc
typedef unsigned short u16;

#define MFMA16(a, b, c) __builtin_amdgcn_mfma_f32_16x16x32_bf16((a), (b), (c), 0, 0, 0)

__device__ __forceinline__ float bf2f(u16 u) {
  union { unsigned int i; float f; } c; c.i = ((unsigned int)u) << 16; return c.f;
}
__device__ __forceinline__ u16 f2bf(float f) {  // RNE
  union { float f; unsigned int i; } c; c.f = f;
  unsigned int i = c.i;
  return (u16)((i + 0x7FFFu + ((i >> 16) & 1u)) >> 16);
}

__device__ __forceinline__ void gld16(const void* g, void* lds) {
  __builtin_amdgcn_global_load_lds(
      (const __attribute__((address_space(1))) void*)g,
      (__attribute__((address_space(3))) void*)lds, 16, 0, 0);
}

// ---------------- split x into hi/lo bf16 ----------------
__global__ __launch_bounds__(256) void k_split_x(
    const float* __restrict__ x, u16* __restrict__ xh, u16* __restrict__ xl) {
  int i = (blockIdx.x * 256 + threadIdx.x) * 4;
  float4 v = *(const float4*)(x + i);
  float vv[4] = {v.x, v.y, v.z, v.w};
  ushort4 h, l;
  u16 hh[4], ll[4];
#pragma unroll
  for (int j = 0; j < 4; j++) {
    hh[j] = f2bf(vv[j]);
    ll[j] = f2bf(vv[j] - bf2f(hh[j]));
  }
  h.x = hh[0]; h.y = hh[1]; h.z = hh[2]; h.w = hh[3];
  l.x = ll[0]; l.y = ll[1]; l.z = ll[2]; l.w = ll[3];
  *(ushort4*)(xh + i) = h;
  *(ushort4*)(xl + i) = l;
}

// ------- transpose + split the 6 weight matrices: Wt[n][k] hi (all), lo (w<4) -------
__global__ __launch_bounds__(256) void k_wsplit(
    const float* __restrict__ W0, const float* __restrict__ W1,
    const float* __restrict__ W2, const float* __restrict__ W3,
    const float* __restrict__ W4, const float* __restrict__ W5,
    u16* __restrict__ wth, u16* __restrict__ wtl) {
  __shared__ float tile[64][65];
  int wz = blockIdx.z;
  const float* W = wz == 0 ? W0 : wz == 1 ? W1 : wz == 2 ? W2 : wz == 3 ? W3 : wz == 4 ? W4 : W5;
  int kb = blockIdx.x * 64, nb = blockIdx.y * 64;
  int t = threadIdx.x;
  int r0 = t >> 4, c0 = (t & 15) * 4;
#pragma unroll
  for (int i = 0; i < 4; i++) {
    int r = r0 + i * 16;
    float4 v = *(const float4*)(W + (size_t)(kb + r) * CDIM + nb + c0);
    tile[r][c0 + 0] = v.x; tile[r][c0 + 1] = v.y; tile[r][c0 + 2] = v.z; tile[r][c0 + 3] = v.w;
  }
  __syncthreads();
#pragma unroll
  for (int i = 0; i < 4; i++) {
    int wn = (t >> 4) + i * 16;   // n within tile
    int wk = (t & 15) * 4;        // k within tile
    ushort4 h, l;
    u16 hh[4], ll[4];
#pragma unroll
    for (int j = 0; j < 4; j++) {
      float v = tile[wk + j][wn];
      hh[j] = f2bf(v);
      ll[j] = f2bf(v - bf2f(hh[j]));
    }
    h.x = hh[0]; h.y = hh[1]; h.z = hh[2]; h.w = hh[3];
    l.x = ll[0]; l.y = ll[1]; l.z = ll[2]; l.w = ll[3];
    size_t off = ((size_t)wz * CDIM + nb + wn) * CDIM + kb + wk;
    *(ushort4*)(wth + off) = h;
    if (wz < 4) *(ushort4*)(wtl + off) = l;
  }
}

// ------------- fused 5-projection GEMM: P_w = x + x@W_w + b_w -------------
// grid (40,16): w = bx/8, 128x128 tile.  w<4: 3 split phases, split output.
// w==4: 1 phase, output transposed bf16 (vT[c][n]) for PV B-fragments.
__global__ __launch_bounds__(256, 2) void k_proj(
    const u16* __restrict__ xh, const u16* __restrict__ xl,
    const u16* __restrict__ wth, const u16* __restrict__ wtl,
    const float* __restrict__ x,
    const float* __restrict__ b0, const float* __restrict__ b1,
    const float* __restrict__ b2, const float* __restrict__ b3,
    const float* __restrict__ b4,
    u16* __restrict__ qh, u16* __restrict__ ql, u16* __restrict__ vT) {
  __shared__ u16 sA[128 * 64];
  __shared__ u16 sB[128 * 64];
  int t = threadIdx.x;
  int w = blockIdx.x >> 3;
  int n0 = (blockIdx.x & 7) * 128;
  int m0 = blockIdx.y * 128;
  int lane = t & 63, wid = t >> 6;
  int wm = (wid >> 1) * 64, wn = (wid & 1) * 64;
  int lr = lane & 15, lg = lane >> 4;

  f4 acc[4][4];
#pragma unroll
  for (int i = 0; i < 4; i++)
#pragma unroll
    for (int j = 0; j < 4; j++) acc[i][j] = (f4)0.0f;

  const int nphase = (w < 4) ? 3 : 1;
  const u16* wb = wth + (size_t)w * CDIM * CDIM;
  const u16* wl = wtl + (size_t)w * CDIM * CDIM;

  int srow = t >> 3;          // 0..31
  int scol = (t & 7) * 8;     // elem col
  int soff = srow * 64 + scol;

  for (int p = 0; p < nphase; p++) {
    const u16* A = (p == 2) ? xl : xh;
    const u16* B = (p == 1) ? wl : wb;
    for (int kt = 0; kt < CDIM; kt += 64) {
#pragma unroll
      for (int c = 0; c < 4; c++) {
        gld16(A + (size_t)(m0 + srow + c * 32) * CDIM + kt + scol, (u16*)sA + soff + c * 2048);
        gld16(B + (size_t)(n0 + srow + c * 32) * CDIM + kt + scol, (u16*)sB + soff + c * 2048);
      }
      __syncthreads();
#pragma unroll
      for (int kk = 0; kk < 2; kk++) {
        bfrag af[4], bv[4];
#pragma unroll
        for (int mi = 0; mi < 4; mi++)
          af[mi] = *(const bfrag*)(sA + (wm + mi * 16 + lr) * 64 + kk * 32 + lg * 8);
#pragma unroll
        for (int ni = 0; ni < 4; ni++)
          bv[ni] = *(const bfrag*)(sB + (wn + ni * 16 + lr) * 64 + kk * 32 + lg * 8);
#pragma unroll
        for (int mi = 0; mi < 4; mi++)
#pragma unroll
          for (int ni = 0; ni < 4; ni++)
            acc[mi][ni] = MFMA16(af[mi], bv[ni], acc[mi][ni]);
      }
      __syncthreads();
    }
  }

  const float* bias = w == 0 ? b0 : w == 1 ? b1 : w == 2 ? b2 : w == 3 ? b3 : b4;
#pragma unroll
  for (int mi = 0; mi < 4; mi++) {
#pragma unroll
    for (int ni = 0; ni < 4; ni++) {
      int col = n0 + wn + ni * 16 + lr;       // 0..1023 within this weight
      int rowb = m0 + wm + mi * 16 + lg * 4;
      float vv[4];
#pragma unroll
      for (int r = 0; r < 4; r++)
        vv[r] = acc[mi][ni][r] + x[(size_t)(rowb + r) * CDIM + col] + bias[col];
      if (w < 4) {
#pragma unroll
        for (int r = 0; r < 4; r++) {
          u16 h = f2bf(vv[r]);
          u16 l = f2bf(vv[r] - bf2f(h));
          qh[((size_t)w * N_SEQ + rowb + r) * CDIM + col] = h;
          ql[((size_t)w * N_SEQ + rowb + r) * CDIM + col] = l;
        }
      } else {
        ushort4 pv;
        pv.x = f2bf(vv[0]); pv.y = f2bf(vv[1]); pv.z = f2bf(vv[2]); pv.w = f2bf(vv[3]);
        *(ushort4*)(vT + (size_t)col * N_SEQ + rowb) = pv;
      }
    }
  }
}

// ---------------- flash attention, split-bf16 scores, LDS-staged K ----------------
// grid 512 (XCD-swizzled: 2 heads per XCD -> K/V L2-resident).
// Block: 4 waves x 16 q-rows = 64 q-rows, one head.
// K tiles (k1h,k1l,k2h,k2l; 32 rows) double-buffered in LDS via global_load_lds,
// 2-phase pipeline (issue next tile's loads BEFORE computing current tile).
// V direct from global (L2). P transposed via 1KB/wave XOR-swizzled LDS bounce.
__global__ __launch_bounds__(256, 2) void k_attn(
    const u16* __restrict__ qkh, const u16* __restrict__ qkl,
    const u16* __restrict__ vT, float* __restrict__ o) {
  __shared__ u16 sbuf[2][16 * 512];   // [buf][chunk 0..15][lane*8]; chunk = (tt*4+kvh*2+ks)
  __shared__ u16 pbuf[4][512];        // per-wave 1KB swizzled P tile (16q x 32k bf16)
  int bid = blockIdx.x;
  int vb = (bid & 7) * 64 + (bid >> 3);   // bijective XCD swizzle (512 % 8 == 0)
  int h = vb >> 5;
  int qb = (vb & 31) * 64;
  int t = threadIdx.x, lane = t & 63, wv = t >> 6, lr = lane & 15, lg = lane >> 4;
  const size_t NC = (size_t)N_SEQ * CDIM;

  const u16* q1h = qkh;          const u16* q1l = qkl;
  const u16* q2h = qkh + NC;     const u16* q2l = qkl + NC;
  // this wave stages tensor wv of {k1h,k1l,k2h,k2l}:
  const u16* kb = ((wv & 1) ? qkl : qkh) + (size_t)(2 + (wv >> 1)) * NC;

  int qrow = qb + wv * 16 + lr;
  size_t qoff = (size_t)qrow * CDIM + h * HDIM + lg * 8;
  bfrag a1h[2], a1l[2], a2h[2], a2l[2];
#pragma unroll
  for (int ks = 0; ks < 2; ks++) {
    a1h[ks] = *(const bfrag*)(q1h + qoff + ks * 32);
    a1l[ks] = *(const bfrag*)(q1l + qoff + ks * 32);
    a2h[ks] = *(const bfrag*)(q2h + qoff + ks * 32);
    a2l[ks] = *(const bfrag*)(q2l + qoff + ks * 32);
  }

  float mrow[4], lrow[4];
  f4 accO[4];
#pragma unroll
  for (int r = 0; r < 4; r++) { mrow[r] = -1e30f; lrow[r] = 0.f; }
#pragma unroll
  for (int d = 0; d < 4; d++) accO[d] = (f4)0.0f;

  u16* pbw = &pbuf[wv][0];

#define STAGE(bufidx, ktv)                                                         \
  {                                                                                \
    _Pragma("unroll")                                                              \
    for (int i = 0; i < 4; i++) {                                                  \
      int kvh = i >> 1, ks = i & 1;                                                \
      const u16* src = kb + (size_t)((ktv) + kvh * 16 + lr) * CDIM +               \
                       h * HDIM + ks * 32 + lg * 8;                                \
      gld16(src, &sbuf[bufidx][(wv * 4 + i) * 512]);                               \
    }                                                                              \
  }

#define KF(sb_, tt, kvh, ks) \
  (*(const bfrag*)((sb_) + (((tt)*4 + (kvh)*2 + (ks)) * 512) + lane * 8))

  STAGE(0, 0);
  __syncthreads();

  for (int it = 0; it < N_SEQ / 32; it++) {
    int kt = it * 32;
    if (it < N_SEQ / 32 - 1) STAGE((it + 1) & 1, kt + 32);

    const u16* sb = &sbuf[it & 1][0];
    f4 s1[2], s2[2];
#pragma unroll
    for (int i = 0; i < 2; i++) { s1[i] = (f4)0.0f; s2[i] = (f4)0.0f; }
#pragma unroll
    for (int kvh = 0; kvh < 2; kvh++) {
#pragma unroll
      for (int ks = 0; ks < 2; ks++) {
        bfrag b1h = KF(sb, 0, kvh, ks);
        bfrag b1l = KF(sb, 1, kvh, ks);
        bfrag b2h = KF(sb, 2, kvh, ks);
        bfrag b2l = KF(sb, 3, kvh, ks);
        s1[kvh] = MFMA16(a1h[ks], b1h, s1[kvh]);
        s1[kvh] = MFMA16(a1h[ks], b1l, s1[kvh]);
        s1[kvh] = MFMA16(a1l[ks], b1h, s1[kvh]);
        s2[kvh] = MFMA16(a2h[ks], b2h, s2[kvh]);
        s2[kvh] = MFMA16(a2h[ks], b2l, s2[kvh]);
        s2[kvh] = MFMA16(a2l[ks], b2h, s2[kvh]);
      }
    }
    s1[0] *= s2[0];
    s1[1] *= s2[1];
    // online softmax; rows = lg*4+r, cols = kvh*16+lr
#pragma unroll
    for (int r = 0; r < 4; r++) {
      float pm = fmaxf(s1[0][r], s1[1][r]);
#pragma unroll
      for (int d = 1; d < 16; d <<= 1) pm = fmaxf(pm, __shfl_xor(pm, d, 64));
      float mnew = fmaxf(mrow[r], pm);
      float scale = __expf(mrow[r] - mnew);
      mrow[r] = mnew;
      float p0 = __expf(s1[0][r] - mnew);
      float p1 = __expf(s1[1][r] - mnew);
      s1[0][r] = p0; s1[1][r] = p1;
      float rs = p0 + p1;
#pragma unroll
      for (int d = 1; d < 16; d <<= 1) rs += __shfl_xor(rs, d, 64);
      lrow[r] = lrow[r] * scale + rs;
#pragma unroll
      for (int dg = 0; dg < 4; dg++) accO[dg][r] *= scale;
    }
    // P -> per-wave LDS bounce (bf16), XOR-swizzled (bijective, ~2-way banks)
#pragma unroll
    for (int kvh = 0; kvh < 2; kvh++) {
#pragma unroll
      for (int r = 0; r < 4; r++) {
        int q = lg * 4 + r, k = kvh * 16 + lr;
        *(u16*)((char*)pbw + ((q * 64 + k * 2) ^ ((q & 7) << 4))) = f2bf(s1[kvh][r]);
      }
    }
    // PV: A-frag from pbuf, B-frag straight from vT (16B contiguous, L2)
    {
      bfrag pa = *(const bfrag*)((char*)pbw + ((lr * 64 + lg * 16) ^ ((lr & 7) << 4)));
#pragma unroll
      for (int dg = 0; dg < 4; dg++) {
        bfrag vbf = *(const bfrag*)(vT + (size_t)(h * HDIM + dg * 16 + lr) * N_SEQ + kt + lg * 8);
        accO[dg] = MFMA16(pa, vbf, accO[dg]);
      }
    }
    __syncthreads();
  }
#undef STAGE
#undef KF

#pragma unroll
  for (int dg = 0; dg < 4; dg++) {
#pragma unroll
    for (int r = 0; r < 4; r++) {
      int row = qb + wv * 16 + lg * 4 + r;
      int col = h * HDIM + dg * 16 + lr;
      o[(size_t)row * CDIM + col] = accO[dg][r] / lrow[r];
    }
  }
}

// ---------------- LayerNorm (one row per block) ----------------
__global__ __launch_bounds__(256) void k_ln(
    const float* __restrict__ o, const float* __restrict__ g,
    const float* __restrict__ b, u16* __restrict__ oln) {
  __shared__ float rs[4], rs2[4];
  int row = blockIdx.x, t = threadIdx.x;
  float4 v = *(const float4*)(o + (size_t)row * CDIM + t * 4);
  float s = v.x + v.y + v.z + v.w;
  float s2 = v.x * v.x + v.y * v.y + v.z * v.z + v.w * v.w;
#pragma unroll
  for (int d = 1; d < 64; d <<= 1) {
    s += __shfl_xor(s, d, 64);
    s2 += __shfl_xor(s2, d, 64);
  }
  int wv = t >> 6;
  if ((t & 63) == 0) { rs[wv] = s; rs2[wv] = s2; }
  __syncthreads();
  s = rs[0] + rs[1] + rs[2] + rs[3];
  s2 = rs2[0] + rs2[1] + rs2[2] + rs2[3];
  float mu = s * (1.0f / CDIM);
  float var = s2 * (1.0f / CDIM) - mu * mu;
  float inv = rsqrtf(var + 1e-5f);
  float vals[4] = {v.x, v.y, v.z, v.w};
  ushort4 r4;
  u16 rr[4];
#pragma unroll
  for (int j = 0; j < 4; j++) {
    int col = t * 4 + j;
    rr[j] = f2bf((vals[j] - mu) * inv * g[col] + b[col]);
  }
  r4.x = rr[0]; r4.y = rr[1]; r4.z = rr[2]; r4.w = rr[3];
  *(ushort4*)(oln + (size_t)row * CDIM + t * 4) = r4;
}

// ---------------- out = oln @ W_out + b_out (plain bf16) ----------------
__global__ __launch_bounds__(256, 2) void k_ogemm(
    const u16* __restrict__ A, const u16* __restrict__ Bw,
    const float* __restrict__ bias, float* __restrict__ out) {
  __shared__ u16 sA[128 * 64];
  __shared__ u16 sB[128 * 64];
  int t = threadIdx.x;
  int n0 = blockIdx.x * 128, m0 = blockIdx.y * 128;
  int lane = t & 63, wid = t >> 6;
  int wm = (wid >> 1) * 64, wn = (wid & 1) * 64;
  int lr = lane & 15, lg = lane >> 4;
  f4 acc[4][4];
#pragma unroll
  for (int i = 0; i < 4; i++)
#pragma unroll
    for (int j = 0; j < 4; j++) acc[i][j] = (f4)0.0f;
  int srow = t >> 3, scol = (t & 7) * 8, soff = srow * 64 + scol;
  for (int kt = 0; kt < CDIM; kt += 64) {
#pragma unroll
    for (int c = 0; c < 4; c++) {
      gld16(A + (size_t)(m0 + srow + c * 32) * CDIM + kt + scol, (u16*)sA + soff + c * 2048);
      gld16(Bw + (size_t)(n0 + srow + c * 32) * CDIM + kt + scol, (u16*)sB + soff + c * 2048);
    }
    __syncthreads();
#pragma unroll
    for (int kk = 0; kk < 2; kk++) {
      bfrag af[4], bv[4];
#pragma unroll
      for (int mi = 0; mi < 4; mi++)
        af[mi] = *(const bfrag*)(sA + (wm + mi * 16 + lr) * 64 + kk * 32 + lg * 8);
#pragma unroll
      for (int ni = 0; ni < 4; ni++)
        bv[ni] = *(const bfrag*)(sB + (wn + ni * 16 + lr) * 64 + kk * 32 + lg * 8);
#pragma unroll
      for (int mi = 0; mi < 4; mi++)
#pragma unroll
        for (int ni = 0; ni < 4; ni++)
          acc[mi][ni] = MFMA16(af[mi], bv[ni], acc[mi][ni]);
    }
    __syncthreads();
  }
#pragma unroll
  for (int mi = 0; mi < 4; mi++) {
#pragma unroll
    for (int ni = 0; ni < 4; ni++) {
      int col = n0 + wn + ni * 16 + lr;
      int rowb = m0 + wm + mi * 16 + lg * 4;
#pragma unroll
      for (int r = 0; r < 4; r++)
        out[(size_t)(rowb + r) * CDIM + col] = acc[mi][ni][r] + bias[col];
    }
  }
}

extern "C" void kernel_launch(void* const* d_in, const int* in_sizes, int n_in,
                              void* d_out, int out_size, void* d_ws, size_t ws_size,
                              hipStream_t stream) {
  const float* x   = (const float*)d_in[0];
  const float* Wq1 = (const float*)d_in[1];  const float* bq1 = (const float*)d_in[2];
  const float* Wq2 = (const float*)d_in[3];  const float* bq2 = (const float*)d_in[4];
  const float* Wk1 = (const float*)d_in[5];  const float* bk1 = (const float*)d_in[6];
  const float* Wk2 = (const float*)d_in[7];  const float* bk2 = (const float*)d_in[8];
  const float* Wv  = (const float*)d_in[9];  const float* bv  = (const float*)d_in[10];
  const float* Wo  = (const float*)d_in[11]; const float* bo  = (const float*)d_in[12];
  const float* lng = (const float*)d_in[13]; const float* lnb = (const float*)d_in[14];

  char* w = (char*)d_ws;  // 64 MiB total, with two safe aliases
  u16* xh  = (u16*)(w + (0ull << 20));    // 4 MiB
  u16* xl  = (u16*)(w + (4ull << 20));    // 4 MiB
  u16* wth = (u16*)(w + (8ull << 20));    // 12 MiB [6][C][C]
  u16* wtl = (u16*)(w + (20ull << 20));   // 8 MiB  [4][C][C]
  u16* qsh = (u16*)(w + (28ull << 20));   // 16 MiB [4][N][C]  q1,q2,k1,k2 hi
  u16* qsl = (u16*)(w + (44ull << 20));   // 16 MiB lo
  u16* vT  = (u16*)(w + (60ull << 20));   // 4 MiB  [C][N]
  float* o = (float*)(w + (0ull << 20));  // 8 MiB, aliases xh/xl (dead after proj)
  u16* oln = (u16*)(w + (20ull << 20));   // 4 MiB, aliases wtl (dead after proj)

  k_split_x<<<2048, 256, 0, stream>>>(x, xh, xl);
  k_wsplit<<<dim3(16, 16, 6), 256, 0, stream>>>(Wq1, Wq2, Wk1, Wk2, Wv, Wo, wth, wtl);
  k_proj<<<dim3(40, 16), 256, 0, stream>>>(xh, xl, wth, wtl, x,
                                           bq1, bq2, bk1, bk2, bv, qsh, qsl, vT);
  k_attn<<<512, 256, 0, stream>>>(qsh, qsl, vT, o);
  k_ln<<<2048, 256, 0, stream>>>(o, lng, lnb, oln);
  k_ogemm<<<dim3(8, 16), 256, 0, stream>>>(oln, wth + 5ull * CDIM * CDIM, bo, (float*)d_out);
}